// Round 5
// baseline (8292.191 us; speedup 1.0000x reference)
//
#include <hip/hip_runtime.h>

#define B_ 256
#define S_ 512
#define E_ 128
#define H_ 256
#define FH_ 1024
#define WROW 264  // 256 + 8 pad (shorts) -> row pitch 132 dwords = 4 mod 32

typedef __bf16 bf16x8 __attribute__((ext_vector_type(8)));
typedef float f32x4 __attribute__((ext_vector_type(4)));
typedef unsigned short u16x4 __attribute__((ext_vector_type(4)));
typedef unsigned short u16x8 __attribute__((ext_vector_type(8)));

__device__ __forceinline__ unsigned short f2bf(float f) {
  union { float f; unsigned int u; } a; a.f = f;
  unsigned int u = a.u;
  u += 0x7fffu + ((u >> 16) & 1u);  // RNE
  return (unsigned short)(u >> 16);
}
__device__ __forceinline__ float bf2f(unsigned short v) {
  union { unsigned int u; float f; } a; a.u = ((unsigned int)v) << 16;
  return a.f;
}
__device__ __forceinline__ float sigm(float x) { return 1.f / (1.f + __expf(-x)); }
__device__ __forceinline__ float tanh_(float x) {
  float e = __expf(2.f * x);
  return 1.f - 2.f / (e + 1.f);
}

// ---------------- workspace layout (bytes) ----------------
#define OFF_ENC    ((size_t)0)          // enc_out bf16 [256][512][256]  67108864
#define OFF_WHHE   ((size_t)67108864)   // enc_Whh bf16 [1024][256]        524288
#define OFF_WHHP   ((size_t)67633152)   // pb_Whh  bf16                    524288
#define OFF_WREF   ((size_t)68157440)   // Wref    bf16 [256][256]         131072
#define OFF_MENC   ((size_t)68288512)   // M = enc_Wih@W_emb f32 [1024][2]   8192
#define OFF_BIASE  ((size_t)68296704)   // enc_bih+enc_bhh f32 [1024]        4096
#define OFF_XPV    ((size_t)68300800)   // pb x-projection f32 [1024]        4096
#define OFF_FLAGS  ((size_t)68304896)   // u32 flags (unused by k1 now)      1024
#define OFF_HX     ((size_t)68305920)   // (unused)                        262144
#define OFF_HFIN   ((size_t)68568064)   // final h f32 [256][256]          262144
#define OFF_QBUF   ((size_t)68830208)   // q f32 [256][256]                262144
#define OFF_UBUF   ((size_t)69092352)   // u f32 [256][512]                524288

// ---------------- K0: prep (weight conversion, folded projections, zeroing) ----
__global__ void k0_prep(const float* __restrict__ eWih, const float* __restrict__ eWhh,
                        const float* __restrict__ ebih, const float* __restrict__ ebhh,
                        const float* __restrict__ pWih, const float* __restrict__ pWhh,
                        const float* __restrict__ pbih, const float* __restrict__ pbhh,
                        const float* __restrict__ W_emb, const float* __restrict__ dec_in,
                        const float* __restrict__ Wref,
                        unsigned short* __restrict__ WhhE, unsigned short* __restrict__ WhhP,
                        unsigned short* __restrict__ Wrefb,
                        float* __restrict__ Menc, float* __restrict__ biasE,
                        float* __restrict__ xpv,
                        unsigned int* __restrict__ flags, float* __restrict__ ubuf) {
  int gid = blockIdx.x * blockDim.x + threadIdx.x;
  int NT = gridDim.x * blockDim.x;
  for (int i = gid; i < FH_ * H_; i += NT) {
    WhhE[i] = f2bf(eWhh[i]);
    WhhP[i] = f2bf(pWhh[i]);
  }
  for (int i = gid; i < H_ * H_; i += NT) Wrefb[i] = f2bf(Wref[i]);
  for (int i = gid; i < B_ * S_; i += NT) ubuf[i] = 0.f;
  if (gid < 256) flags[gid] = 0u;
  if (gid < FH_) {
    int n = gid;
    float m0 = 0.f, m1 = 0.f, xs = 0.f;
    for (int e = 0; e < E_; ++e) {
      float w = eWih[n * E_ + e];
      m0 += w * W_emb[e * 2 + 0];
      m1 += w * W_emb[e * 2 + 1];
      xs += pWih[n * E_ + e] * dec_in[e];
    }
    Menc[n * 2 + 0] = m0;
    Menc[n * 2 + 1] = m1;
    biasE[n] = ebih[n] + ebhh[n];
    xpv[n] = xs + pbih[n] + pbhh[n];
  }
}

// ---------------- K1: self-contained dual-LSTM recurrence ----------------
// 16 WGs x 1024 threads (16 waves = 4/SIMD). Each WG owns 16 batch rows and
// ALL 1024 gate columns; full Whh (512KB bf16) register-resident at 128
// VGPR/thread. amdgpu_waves_per_eu(4,4) pins the allocator budget to 256
// regs/wave so the weight array cannot be spilled for occupancy.
// ZERO cross-WG communication: rounds 0-4 proved the per-step agent-scope
// release/acquire (L2 wb + inv per poll) generates ~1.6 GB/ms of L2 refetch
// and dominates the runtime regardless of where the weights live.
// h exchange is a pure-LDS double buffer, ONE __syncthreads per step.
// Floor: 137 GFLOP on 16 CUs ~ 875 us (MFMA-pipe-bound).
__launch_bounds__(1024)
__attribute__((amdgpu_waves_per_eu(4, 4)))
__global__ void k1_lstm(const float* __restrict__ inp,
                        const unsigned short* __restrict__ WhhE,
                        const unsigned short* __restrict__ WhhP,
                        const float* __restrict__ Menc, const float* __restrict__ biasE,
                        const float* __restrict__ xpv,
                        unsigned short* __restrict__ enc_out,
                        float* __restrict__ hfin) {
  __shared__ unsigned short hbuf[2][16 * WROW];  // h bf16, dbl-buffered
  __shared__ float xin[2][16][2];
  const int tid = threadIdx.x;
  const int wave = tid >> 6, lane = tid & 63, quad = lane >> 4, l16 = lane & 15;
  const int grp = blockIdx.x;        // 0..15 batch group
  const int hc = wave * 16 + l16;    // this lane's h column 0..255

  for (int i = tid; i < 16 * WROW; i += 1024) {
    hbuf[0][i] = 0;
    hbuf[1][i] = 0;
  }
  if (tid < 32)
    xin[0][tid >> 1][tid & 1] = inp[((grp * 16 + (tid >> 1)) * S_ + 0) * 2 + (tid & 1)];

  float c[4] = {0.f, 0.f, 0.f, 0.f};
  float hreg[4] = {0.f, 0.f, 0.f, 0.f};
  bf16x8 Bf[4][8];  // 128 VGPRs of weights: 4 gates x K=256
  float m0c[4], m1c[4], bc[4];
  const f32x4 z4 = {0.f, 0.f, 0.f, 0.f};
  __syncthreads();

  int cur = 0;
#pragma unroll 1
  for (int phase = 0; phase < 2; ++phase) {
    const unsigned short* W = phase ? WhhP : WhhE;
#pragma unroll
    for (int g = 0; g < 4; ++g) {
      int n = g * 256 + hc;  // gate row
#pragma unroll
      for (int kt = 0; kt < 8; ++kt)
        Bf[g][kt] = *(const bf16x8*)(W + n * H_ + kt * 32 + quad * 8);
      if (phase == 0) {
        m0c[g] = Menc[n * 2 + 0]; m1c[g] = Menc[n * 2 + 1]; bc[g] = biasE[n];
      } else {
        m0c[g] = 0.f; m1c[g] = 0.f; bc[g] = xpv[n];
      }
    }
#pragma unroll 1
    for (int step = 0; step < 512; ++step) {
      // ---- GEMM: g = h @ Whh^T, this wave's 16 h-cols x 4 gates, K=256 ----
      f32x4 acc[4];
#pragma unroll
      for (int kt = 0; kt < 8; ++kt) {
        bf16x8 Af = *(const bf16x8*)(hbuf[cur] + l16 * WROW + kt * 32 + quad * 8);
#pragma unroll
        for (int g = 0; g < 4; ++g)
          acc[g] = __builtin_amdgcn_mfma_f32_16x16x32_bf16(
              Af, Bf[g][kt], (kt == 0) ? z4 : acc[g], 0, 0, 0);
      }
      // ---- gates: lane owns batch rows quad*4+r, h-col hc ----
      unsigned short hb[4];
#pragma unroll
      for (int r = 0; r < 4; ++r) {
        int m = quad * 4 + r;
        float x0 = xin[cur][m][0], x1 = xin[cur][m][1];
        float gi = acc[0][r] + x0 * m0c[0] + x1 * m1c[0] + bc[0];
        float gf = acc[1][r] + x0 * m0c[1] + x1 * m1c[1] + bc[1];
        float gc = acc[2][r] + x0 * m0c[2] + x1 * m1c[2] + bc[2];
        float go = acc[3][r] + x0 * m0c[3] + x1 * m1c[3] + bc[3];
        float cn = sigm(gf) * c[r] + sigm(gi) * tanh_(gc);
        c[r] = cn;
        hreg[r] = sigm(go) * tanh_(cn);
        hb[r] = f2bf(hreg[r]);
      }
      if (phase == 0) {
#pragma unroll
        for (int r = 0; r < 4; ++r)
          enc_out[(((size_t)(grp * 16 + quad * 4 + r) * S_ + step)) * H_ + hc] = hb[r];
      }
      // ---- write next h into the other LDS buffer ----
#pragma unroll
      for (int r = 0; r < 4; ++r) hbuf[cur ^ 1][(quad * 4 + r) * WROW + hc] = hb[r];
      if (phase == 0 && step < 511 && tid < 32)
        xin[cur ^ 1][tid >> 1][tid & 1] =
            inp[((grp * 16 + (tid >> 1)) * S_ + (step + 1)) * 2 + (tid & 1)];
      __syncthreads();  // h(t+1) ready for all waves
      cur ^= 1;
    }
  }
  // final h (fp32) for the attention query
#pragma unroll
  for (int r = 0; r < 4; ++r)
    hfin[(grp * 16 + quad * 4 + r) * H_ + hc] = hreg[r];
}

// ---------------- K1b: q = h @ Wq^T + bq (fp32) ----------------
__global__ void k1b_q(const float* __restrict__ hfin, const float* __restrict__ Wq,
                      const float* __restrict__ bq, float* __restrict__ qbuf) {
  __shared__ float hl[H_];
  int b = blockIdx.x, j = threadIdx.x;
  hl[j] = hfin[b * H_ + j];
  __syncthreads();
  float s = bq[j];
  const float* w = Wq + j * H_;
  for (int k = 0; k < H_; ++k) s += hl[k] * w[k];
  qbuf[b * H_ + j] = s;
}

// ---------------- K2: u = tanh(enc_out@Wref^T + bref + q) @ V (fused) ----------
__launch_bounds__(512)
__global__ void k2_att(const unsigned short* __restrict__ enc_out,
                       const unsigned short* __restrict__ Wrefb,
                       const float* __restrict__ qbuf, const float* __restrict__ bref,
                       const float* __restrict__ V, float* __restrict__ ubuf) {
  __shared__ unsigned short Bs[128 * WROW];
  __shared__ float qs[128], Vs[128];
  int tid = threadIdx.x;
  int wave = tid >> 6, lane = tid & 63, quad = lane >> 4, l16 = lane & 15;
  int rowblk = blockIdx.x >> 1, nb = blockIdx.x & 1;
  int b = rowblk >> 2;
  {  // stage Wref block [nb*128 .. +128) x 256 into LDS
    int nl = tid >> 2, seg = tid & 3;
    const unsigned short* src = Wrefb + (nb * 128 + nl) * H_ + seg * 64;
    unsigned short* dst = Bs + nl * WROW + seg * 64;
#pragma unroll
    for (int i = 0; i < 8; ++i) *(u16x8*)(dst + i * 8) = *(const u16x8*)(src + i * 8);
  }
  if (tid < 128) {
    int j = nb * 128 + tid;
    qs[tid] = qbuf[b * H_ + j] + bref[j];
    Vs[tid] = V[j];
  }
  __syncthreads();
  int rw = rowblk * 128 + wave * 16 + l16;  // global (b,s) row
  const f32x4 z4 = {0.f, 0.f, 0.f, 0.f};
  f32x4 acc[8];
#pragma unroll
  for (int kt = 0; kt < 8; ++kt) {
    bf16x8 af = *(const bf16x8*)(enc_out + (size_t)rw * H_ + kt * 32 + quad * 8);
#pragma unroll
    for (int nt = 0; nt < 8; ++nt) {
      bf16x8 bfr = *(const bf16x8*)(Bs + (nt * 16 + l16) * WROW + kt * 32 + quad * 8);
      acc[nt] = __builtin_amdgcn_mfma_f32_16x16x32_bf16(af, bfr, (kt == 0) ? z4 : acc[nt],
                                                        0, 0, 0);
    }
  }
  float part[4] = {0.f, 0.f, 0.f, 0.f};
#pragma unroll
  for (int nt = 0; nt < 8; ++nt) {
    float qv = qs[nt * 16 + l16], vv = Vs[nt * 16 + l16];
#pragma unroll
    for (int r = 0; r < 4; ++r) part[r] += tanh_(acc[nt][r] + qv) * vv;
  }
#pragma unroll
  for (int m = 1; m < 16; m <<= 1) {
#pragma unroll
    for (int r = 0; r < 4; ++r) part[r] += __shfl_xor(part[r], m, 64);
  }
  if (l16 == 0) {
    int s0 = (rowblk & 3) * 128 + wave * 16 + quad * 4;
#pragma unroll
    for (int r = 0; r < 4; ++r) atomicAdd(&ubuf[b * S_ + s0 + r], part[r]);
  }
}

// ---------------- K3: softmax + glimpse + decoder head ----------------
__global__ void k3_head(const float* __restrict__ ubuf,
                        const unsigned short* __restrict__ enc_out,
                        const float* __restrict__ Wd1, const float* __restrict__ Wd2,
                        float* __restrict__ out) {
  __shared__ float sm[512];
  __shared__ float red[256];
  __shared__ float gl[256];
  int b = blockIdx.x, tid = threadIdx.x;
  float u0 = ubuf[b * S_ + tid], u1 = ubuf[b * S_ + 256 + tid];
  red[tid] = fmaxf(u0, u1);
  __syncthreads();
  for (int s = 128; s > 0; s >>= 1) {
    if (tid < s) red[tid] = fmaxf(red[tid], red[tid + s]);
    __syncthreads();
  }
  float mx = red[0];
  __syncthreads();
  float e0 = __expf(u0 - mx), e1 = __expf(u1 - mx);
  red[tid] = e0 + e1;
  __syncthreads();
  for (int s = 128; s > 0; s >>= 1) {
    if (tid < s) red[tid] += red[tid + s];
    __syncthreads();
  }
  float inv = 1.f / red[0];
  sm[tid] = e0 * inv;
  sm[256 + tid] = e1 * inv;
  __syncthreads();
  float g = 0.f;
  const unsigned short* eo = enc_out + (size_t)b * S_ * H_ + tid;
  for (int s = 0; s < S_; ++s) g += sm[s] * bf2f(eo[(size_t)s * H_]);
  gl[tid] = g;
  __syncthreads();
  float y = 0.f;
  const float* w = Wd1 + tid * H_;
  for (int j = 0; j < H_; ++j) y += w[j] * gl[j];
  y = fmaxf(y, 0.f) * Wd2[tid];
  red[tid] = y;
  __syncthreads();
  for (int s = 128; s > 0; s >>= 1) {
    if (tid < s) red[tid] += red[tid + s];
    __syncthreads();
  }
  if (tid == 0) out[b] = red[0];
}

extern "C" void kernel_launch(void* const* d_in, const int* in_sizes, int n_in,
                              void* d_out, int out_size, void* d_ws, size_t ws_size,
                              hipStream_t stream) {
  (void)in_sizes; (void)n_in; (void)out_size; (void)ws_size;
  const float* inp    = (const float*)d_in[0];
  const float* W_emb  = (const float*)d_in[1];
  const float* dec_in = (const float*)d_in[2];
  const float* eWih   = (const float*)d_in[3];
  const float* eWhh   = (const float*)d_in[4];
  const float* ebih   = (const float*)d_in[5];
  const float* ebhh   = (const float*)d_in[6];
  const float* pWih   = (const float*)d_in[7];
  const float* pWhh   = (const float*)d_in[8];
  const float* pbih   = (const float*)d_in[9];
  const float* pbhh   = (const float*)d_in[10];
  const float* Wq     = (const float*)d_in[11];
  const float* bq     = (const float*)d_in[12];
  const float* Wref   = (const float*)d_in[13];
  const float* bref   = (const float*)d_in[14];
  const float* V      = (const float*)d_in[15];
  const float* Wd1    = (const float*)d_in[16];
  const float* Wd2    = (const float*)d_in[17];
  float* out = (float*)d_out;

  char* ws = (char*)d_ws;
  unsigned short* enc_out = (unsigned short*)(ws + OFF_ENC);
  unsigned short* WhhE    = (unsigned short*)(ws + OFF_WHHE);
  unsigned short* WhhP    = (unsigned short*)(ws + OFF_WHHP);
  unsigned short* Wrefb   = (unsigned short*)(ws + OFF_WREF);
  float* Menc  = (float*)(ws + OFF_MENC);
  float* biasE = (float*)(ws + OFF_BIASE);
  float* xpv   = (float*)(ws + OFF_XPV);
  unsigned int* flags = (unsigned int*)(ws + OFF_FLAGS);
  float* hfin = (float*)(ws + OFF_HFIN);
  float* qbuf = (float*)(ws + OFF_QBUF);
  float* ubuf = (float*)(ws + OFF_UBUF);

  hipLaunchKernelGGL(k0_prep, dim3(256), dim3(256), 0, stream,
                     eWih, eWhh, ebih, ebhh, pWih, pWhh, pbih, pbhh, W_emb, dec_in,
                     Wref, WhhE, WhhP, Wrefb, Menc, biasE, xpv, flags, ubuf);
  hipLaunchKernelGGL(k1_lstm, dim3(16), dim3(1024), 0, stream,
                     inp, WhhE, WhhP, Menc, biasE, xpv, enc_out, hfin);
  hipLaunchKernelGGL(k1b_q, dim3(256), dim3(256), 0, stream, hfin, Wq, bq, qbuf);
  hipLaunchKernelGGL(k2_att, dim3(2048), dim3(512), 0, stream,
                     enc_out, Wrefb, qbuf, bref, V, ubuf);
  hipLaunchKernelGGL(k3_head, dim3(256), dim3(256), 0, stream,
                     ubuf, enc_out, Wd1, Wd2, out);
}

// Round 6
// 3865.187 us; speedup vs baseline: 2.1454x; 2.1454x over previous
//
#include <hip/hip_runtime.h>

#define B_ 256
#define S_ 512
#define E_ 128
#define H_ 256
#define FH_ 1024
#define HROW 264  // 256 + 8 pad (shorts) -> row offset 132 dwords = 4 mod 32, conflict-free

typedef __bf16 bf16x8 __attribute__((ext_vector_type(8)));
typedef float f32x4 __attribute__((ext_vector_type(4)));
typedef unsigned short u16x4 __attribute__((ext_vector_type(4)));
typedef unsigned short u16x8 __attribute__((ext_vector_type(8)));

__device__ __forceinline__ unsigned short f2bf(float f) {
  union { float f; unsigned int u; } a; a.f = f;
  unsigned int u = a.u;
  u += 0x7fffu + ((u >> 16) & 1u);  // RNE
  return (unsigned short)(u >> 16);
}
__device__ __forceinline__ float bf2f(unsigned short v) {
  union { unsigned int u; float f; } a; a.u = ((unsigned int)v) << 16;
  return a.f;
}
__device__ __forceinline__ float sigm(float x) { return 1.f / (1.f + __expf(-x)); }
__device__ __forceinline__ float tanh_(float x) {
  float e = __expf(2.f * x);
  return 1.f - 2.f / (e + 1.f);
}

// ---------------- workspace layout (bytes) ----------------
#define OFF_ENC    ((size_t)0)          // enc_out bf16 [256][512][256]  67108864
#define OFF_WHHE   ((size_t)67108864)   // enc_Whh bf16 [1024][256]        524288
#define OFF_WHHP   ((size_t)67633152)   // pb_Whh  bf16                    524288
#define OFF_WREF   ((size_t)68157440)   // Wref    bf16 [256][256]         131072
#define OFF_MENC   ((size_t)68288512)   // M = enc_Wih@W_emb f32 [1024][2]   8192
#define OFF_BIASE  ((size_t)68296704)   // enc_bih+enc_bhh f32 [1024]        4096
#define OFF_XPV    ((size_t)68300800)   // pb x-projection f32 [1024]        4096
#define OFF_FLAGS  ((size_t)68304896)   // u32 flags                         1024
#define OFF_HX     ((size_t)68305920)   // h exchange bf16 [2][16][2][16][128] 262144
#define OFF_HFIN   ((size_t)68568064)   // final h f32 [256][256]          262144
#define OFF_QBUF   ((size_t)68830208)   // q f32 [256][256]                262144
#define OFF_UBUF   ((size_t)69092352)   // u f32 [256][512]                524288

// ---------------- K0: prep (weight conversion, folded projections, zeroing) ----
__global__ void k0_prep(const float* __restrict__ eWih, const float* __restrict__ eWhh,
                        const float* __restrict__ ebih, const float* __restrict__ ebhh,
                        const float* __restrict__ pWih, const float* __restrict__ pWhh,
                        const float* __restrict__ pbih, const float* __restrict__ pbhh,
                        const float* __restrict__ W_emb, const float* __restrict__ dec_in,
                        const float* __restrict__ Wref,
                        unsigned short* __restrict__ WhhE, unsigned short* __restrict__ WhhP,
                        unsigned short* __restrict__ Wrefb,
                        float* __restrict__ Menc, float* __restrict__ biasE,
                        float* __restrict__ xpv,
                        unsigned int* __restrict__ flags, float* __restrict__ ubuf) {
  int gid = blockIdx.x * blockDim.x + threadIdx.x;
  int NT = gridDim.x * blockDim.x;
  for (int i = gid; i < FH_ * H_; i += NT) {
    WhhE[i] = f2bf(eWhh[i]);
    WhhP[i] = f2bf(pWhh[i]);
  }
  for (int i = gid; i < H_ * H_; i += NT) Wrefb[i] = f2bf(Wref[i]);
  for (int i = gid; i < B_ * S_; i += NT) ubuf[i] = 0.f;
  if (gid < 256) flags[gid] = 0u;
  if (gid < FH_) {
    int n = gid;
    float m0 = 0.f, m1 = 0.f, xs = 0.f;
    for (int e = 0; e < E_; ++e) {
      float w = eWih[n * E_ + e];
      m0 += w * W_emb[e * 2 + 0];
      m1 += w * W_emb[e * 2 + 1];
      xs += pWih[n * E_ + e] * dec_in[e];
    }
    Menc[n * 2 + 0] = m0;
    Menc[n * 2 + 1] = m1;
    biasE[n] = ebih[n] + ebhh[n];
    xpv[n] = xs + pbih[n] + pbhh[n];
  }
}

// ---------------- K1: persistent dual-LSTM recurrence ----------------
// 32 WGs x 512 threads (R2/R3 proven structure). Pair of WGs (halves) split
// the 1024 gate columns; each WG's Whh half slice (512B/thread) resident in
// VGPRs as 32 INDIVIDUALLY-NAMED bf16x8 SSA values.
// WHY NAMED: rounds 0-5 proved the aggregate `bf16x8 Bf[4][8]` is demoted to
// scratch before regalloc (VGPR_Count 64..108 in every variant; FETCH_SIZE =
// exactly sizeof(Bf) x threads x steps = 6-8 GB of per-step scratch reload).
// launch_bounds/volatile/waves_per_eu never moved it -> kill the aggregate.
// amdgpu_waves_per_eu(2,2): allocator budget 256 regs (128 weights + ~80 work).
// Handshake: byte-identical proven release/acquire protocol.
__launch_bounds__(512)
__attribute__((amdgpu_waves_per_eu(2, 2)))
__global__ void k1_lstm(const float* __restrict__ inp,
                        const unsigned short* __restrict__ WhhE,
                        const unsigned short* __restrict__ WhhP,
                        const float* __restrict__ Menc, const float* __restrict__ biasE,
                        const float* __restrict__ xpv,
                        unsigned short* __restrict__ enc_out,
                        unsigned short* __restrict__ hx,
                        unsigned int* __restrict__ flags,
                        float* __restrict__ hfin) {
  __shared__ unsigned short hbuf[16 * HROW];  // h bf16, 16 rows x (256+pad)
  __shared__ float xin[16][2];
  const int tid = threadIdx.x;
  const int wave = tid >> 6, lane = tid & 63, quad = lane >> 4, l16 = lane & 15;
  const int blk = blockIdx.x;
  const int grp = (blk & 7) | ((blk >> 4) << 3);  // 0..15
  const int half = (blk >> 3) & 1;
  const int kloc = (wave << 4) | l16;    // 0..127 within half
  const int kcol = half * 128 + kloc;    // 0..255 global h-column

  for (int i = tid; i < 16 * HROW; i += 512) hbuf[i] = 0;
  if (tid < 32) xin[tid >> 1][tid & 1] = inp[((grp * 16 + (tid >> 1)) * S_ + 0) * 2 + (tid & 1)];

  float c[4] = {0.f, 0.f, 0.f, 0.f};
  float hreg[4] = {0.f, 0.f, 0.f, 0.f};
  // 32 named weight fragments (4 gates x 8 k-chunks), 128 VGPRs total.
  bf16x8 B00, B01, B02, B03, B04, B05, B06, B07;
  bf16x8 B10, B11, B12, B13, B14, B15, B16, B17;
  bf16x8 B20, B21, B22, B23, B24, B25, B26, B27;
  bf16x8 B30, B31, B32, B33, B34, B35, B36, B37;
  float m0c[4], m1c[4], bc[4];
  unsigned int* myflag = flags + grp * 2 + half;
  unsigned int* pflag = flags + grp * 2 + (1 - half);
  const f32x4 z4 = {0.f, 0.f, 0.f, 0.f};
  __syncthreads();

  int t = 0;
#pragma unroll 1
  for (int phase = 0; phase < 2; ++phase) {
    const unsigned short* W = phase ? WhhP : WhhE;
#define WLOAD(g)                                                        \
    {                                                                   \
      const unsigned short* wp = W + (g * 256 + kcol) * H_ + quad * 8;  \
      B##g##0 = *(const bf16x8*)(wp + 0 * 32);                          \
      B##g##1 = *(const bf16x8*)(wp + 1 * 32);                          \
      B##g##2 = *(const bf16x8*)(wp + 2 * 32);                          \
      B##g##3 = *(const bf16x8*)(wp + 3 * 32);                          \
      B##g##4 = *(const bf16x8*)(wp + 4 * 32);                          \
      B##g##5 = *(const bf16x8*)(wp + 5 * 32);                          \
      B##g##6 = *(const bf16x8*)(wp + 6 * 32);                          \
      B##g##7 = *(const bf16x8*)(wp + 7 * 32);                          \
    }
    WLOAD(0) WLOAD(1) WLOAD(2) WLOAD(3)
#undef WLOAD
#pragma unroll
    for (int gg = 0; gg < 4; ++gg) {
      int n = gg * 256 + kcol;
      if (phase == 0) {
        m0c[gg] = Menc[n * 2 + 0]; m1c[gg] = Menc[n * 2 + 1]; bc[gg] = biasE[n];
      } else {
        m0c[gg] = 0.f; m1c[gg] = 0.f; bc[gg] = xpv[n];
      }
    }
#pragma unroll 1
    for (int step = 0; step < 512; ++step, ++t) {
      // ---- GEMM: g = h @ Whh^T (this WG's 512 columns) ----
      f32x4 acc0 = z4, acc1 = z4, acc2 = z4, acc3 = z4;
#define MSTEP(kt)                                                                   \
      {                                                                             \
        bf16x8 Af = *(const bf16x8*)(hbuf + l16 * HROW + kt * 32 + quad * 8);       \
        acc0 = __builtin_amdgcn_mfma_f32_16x16x32_bf16(Af, B0##kt, acc0, 0, 0, 0);  \
        acc1 = __builtin_amdgcn_mfma_f32_16x16x32_bf16(Af, B1##kt, acc1, 0, 0, 0);  \
        acc2 = __builtin_amdgcn_mfma_f32_16x16x32_bf16(Af, B2##kt, acc2, 0, 0, 0);  \
        acc3 = __builtin_amdgcn_mfma_f32_16x16x32_bf16(Af, B3##kt, acc3, 0, 0, 0);  \
      }
      MSTEP(0) MSTEP(1) MSTEP(2) MSTEP(3) MSTEP(4) MSTEP(5) MSTEP(6) MSTEP(7)
#undef MSTEP
      // ---- gates (fp32). lane holds rows quad*4+r, column kcol, all 4 gates ----
      unsigned short hb[4];
#pragma unroll
      for (int r = 0; r < 4; ++r) {
        int bl = quad * 4 + r;
        float x0 = xin[bl][0], x1 = xin[bl][1];
        float gi = acc0[r] + x0 * m0c[0] + x1 * m1c[0] + bc[0];
        float gf = acc1[r] + x0 * m0c[1] + x1 * m1c[1] + bc[1];
        float gc = acc2[r] + x0 * m0c[2] + x1 * m1c[2] + bc[2];
        float go = acc3[r] + x0 * m0c[3] + x1 * m1c[3] + bc[3];
        float cn = sigm(gf) * c[r] + sigm(gi) * tanh_(gc);
        c[r] = cn;
        hreg[r] = sigm(go) * tanh_(cn);
        hb[r] = f2bf(hreg[r]);
      }
      // ---- publish own half (global) ----
      if (phase == 0) {
#pragma unroll
        for (int r = 0; r < 4; ++r)
          enc_out[(((size_t)(grp * 16 + quad * 4 + r) * S_ + step)) * H_ + kcol] = hb[r];
      }
      {
        unsigned short* hxs = hx + ((size_t)((t & 1) * 32 + grp * 2 + half)) * 2048;
#pragma unroll
        for (int r = 0; r < 4; ++r) hxs[(quad * 4 + r) * 128 + kloc] = hb[r];
      }
      __syncthreads();  // (a) A-frag reads done; hx stores drained
      if (tid == 0) {
        __hip_atomic_store(myflag, (unsigned int)(t + 1), __ATOMIC_RELEASE,
                           __HIP_MEMORY_SCOPE_AGENT);
        while (__hip_atomic_load(pflag, __ATOMIC_ACQUIRE, __HIP_MEMORY_SCOPE_AGENT) <
               (unsigned int)(t + 1)) {
          __builtin_amdgcn_s_sleep(1);
        }
      }
      __syncthreads();  // (b)
      // ---- update LDS h: own half from regs, peer half from hx ----
#pragma unroll
      for (int r = 0; r < 4; ++r) hbuf[(quad * 4 + r) * HROW + kcol] = hb[r];
      {
        const unsigned short* ph = hx + ((size_t)((t & 1) * 32 + grp * 2 + (1 - half))) * 2048;
        int idx = tid * 4;  // 0..2047
        int prow = idx >> 7, pcol = idx & 127;
        u16x4 v = *(const u16x4*)(ph + idx);
        *(u16x4*)(hbuf + prow * HROW + (1 - half) * 128 + pcol) = v;
      }
      if (phase == 0 && step < 511 && tid < 32)
        xin[tid >> 1][tid & 1] =
            inp[((grp * 16 + (tid >> 1)) * S_ + (step + 1)) * 2 + (tid & 1)];
      __syncthreads();  // (c) h ready for next step
    }
  }
  // final h (fp32) for the attention query
#pragma unroll
  for (int r = 0; r < 4; ++r)
    hfin[(grp * 16 + quad * 4 + r) * H_ + kcol] = hreg[r];
}

// ---------------- K1b: q = h @ Wq^T + bq (fp32) ----------------
__global__ void k1b_q(const float* __restrict__ hfin, const float* __restrict__ Wq,
                      const float* __restrict__ bq, float* __restrict__ qbuf) {
  __shared__ float hl[H_];
  int b = blockIdx.x, j = threadIdx.x;
  hl[j] = hfin[b * H_ + j];
  __syncthreads();
  float s = bq[j];
  const float* w = Wq + j * H_;
  for (int k = 0; k < H_; ++k) s += hl[k] * w[k];
  qbuf[b * H_ + j] = s;
}

// ---------------- K2: u = tanh(enc_out@Wref^T + bref + q) @ V (fused) ----------
__launch_bounds__(512)
__global__ void k2_att(const unsigned short* __restrict__ enc_out,
                       const unsigned short* __restrict__ Wrefb,
                       const float* __restrict__ qbuf, const float* __restrict__ bref,
                       const float* __restrict__ V, float* __restrict__ ubuf) {
  __shared__ unsigned short Bs[128 * HROW];
  __shared__ float qs[128], Vs[128];
  int tid = threadIdx.x;
  int wave = tid >> 6, lane = tid & 63, quad = lane >> 4, l16 = lane & 15;
  int rowblk = blockIdx.x >> 1, nb = blockIdx.x & 1;
  int b = rowblk >> 2;
  {  // stage Wref block [nb*128 .. +128) x 256 into LDS
    int nl = tid >> 2, seg = tid & 3;
    const unsigned short* src = Wrefb + (nb * 128 + nl) * H_ + seg * 64;
    unsigned short* dst = Bs + nl * HROW + seg * 64;
#pragma unroll
    for (int i = 0; i < 8; ++i) *(u16x8*)(dst + i * 8) = *(const u16x8*)(src + i * 8);
  }
  if (tid < 128) {
    int j = nb * 128 + tid;
    qs[tid] = qbuf[b * H_ + j] + bref[j];
    Vs[tid] = V[j];
  }
  __syncthreads();
  int rw = rowblk * 128 + wave * 16 + l16;  // global (b,s) row
  const f32x4 z4 = {0.f, 0.f, 0.f, 0.f};
  f32x4 acc[8];
#pragma unroll
  for (int kt = 0; kt < 8; ++kt) {
    bf16x8 af = *(const bf16x8*)(enc_out + (size_t)rw * H_ + kt * 32 + quad * 8);
#pragma unroll
    for (int nt = 0; nt < 8; ++nt) {
      bf16x8 bfr = *(const bf16x8*)(Bs + (nt * 16 + l16) * HROW + kt * 32 + quad * 8);
      acc[nt] = __builtin_amdgcn_mfma_f32_16x16x32_bf16(af, bfr, (kt == 0) ? z4 : acc[nt],
                                                        0, 0, 0);
    }
  }
  float part[4] = {0.f, 0.f, 0.f, 0.f};
#pragma unroll
  for (int nt = 0; nt < 8; ++nt) {
    float qv = qs[nt * 16 + l16], vv = Vs[nt * 16 + l16];
#pragma unroll
    for (int r = 0; r < 4; ++r) part[r] += tanh_(acc[nt][r] + qv) * vv;
  }
#pragma unroll
  for (int m = 1; m < 16; m <<= 1) {
#pragma unroll
    for (int r = 0; r < 4; ++r) part[r] += __shfl_xor(part[r], m, 64);
  }
  if (l16 == 0) {
    int s0 = (rowblk & 3) * 128 + wave * 16 + quad * 4;
#pragma unroll
    for (int r = 0; r < 4; ++r) atomicAdd(&ubuf[b * S_ + s0 + r], part[r]);
  }
}

// ---------------- K3: softmax + glimpse + decoder head ----------------
__global__ void k3_head(const float* __restrict__ ubuf,
                        const unsigned short* __restrict__ enc_out,
                        const float* __restrict__ Wd1, const float* __restrict__ Wd2,
                        float* __restrict__ out) {
  __shared__ float sm[512];
  __shared__ float red[256];
  __shared__ float gl[256];
  int b = blockIdx.x, tid = threadIdx.x;
  float u0 = ubuf[b * S_ + tid], u1 = ubuf[b * S_ + 256 + tid];
  red[tid] = fmaxf(u0, u1);
  __syncthreads();
  for (int s = 128; s > 0; s >>= 1) {
    if (tid < s) red[tid] = fmaxf(red[tid], red[tid + s]);
    __syncthreads();
  }
  float mx = red[0];
  __syncthreads();
  float e0 = __expf(u0 - mx), e1 = __expf(u1 - mx);
  red[tid] = e0 + e1;
  __syncthreads();
  for (int s = 128; s > 0; s >>= 1) {
    if (tid < s) red[tid] += red[tid + s];
    __syncthreads();
  }
  float inv = 1.f / red[0];
  sm[tid] = e0 * inv;
  sm[256 + tid] = e1 * inv;
  __syncthreads();
  float g = 0.f;
  const unsigned short* eo = enc_out + (size_t)b * S_ * H_ + tid;
  for (int s = 0; s < S_; ++s) g += sm[s] * bf2f(eo[(size_t)s * H_]);
  gl[tid] = g;
  __syncthreads();
  float y = 0.f;
  const float* w = Wd1 + tid * H_;
  for (int j = 0; j < H_; ++j) y += w[j] * gl[j];
  y = fmaxf(y, 0.f) * Wd2[tid];
  red[tid] = y;
  __syncthreads();
  for (int s = 128; s > 0; s >>= 1) {
    if (tid < s) red[tid] += red[tid + s];
    __syncthreads();
  }
  if (tid == 0) out[b] = red[0];
}

extern "C" void kernel_launch(void* const* d_in, const int* in_sizes, int n_in,
                              void* d_out, int out_size, void* d_ws, size_t ws_size,
                              hipStream_t stream) {
  (void)in_sizes; (void)n_in; (void)out_size; (void)ws_size;
  const float* inp    = (const float*)d_in[0];
  const float* W_emb  = (const float*)d_in[1];
  const float* dec_in = (const float*)d_in[2];
  const float* eWih   = (const float*)d_in[3];
  const float* eWhh   = (const float*)d_in[4];
  const float* ebih   = (const float*)d_in[5];
  const float* ebhh   = (const float*)d_in[6];
  const float* pWih   = (const float*)d_in[7];
  const float* pWhh   = (const float*)d_in[8];
  const float* pbih   = (const float*)d_in[9];
  const float* pbhh   = (const float*)d_in[10];
  const float* Wq     = (const float*)d_in[11];
  const float* bq     = (const float*)d_in[12];
  const float* Wref   = (const float*)d_in[13];
  const float* bref   = (const float*)d_in[14];
  const float* V      = (const float*)d_in[15];
  const float* Wd1    = (const float*)d_in[16];
  const float* Wd2    = (const float*)d_in[17];
  float* out = (float*)d_out;

  char* ws = (char*)d_ws;
  unsigned short* enc_out = (unsigned short*)(ws + OFF_ENC);
  unsigned short* WhhE    = (unsigned short*)(ws + OFF_WHHE);
  unsigned short* WhhP    = (unsigned short*)(ws + OFF_WHHP);
  unsigned short* Wrefb   = (unsigned short*)(ws + OFF_WREF);
  float* Menc  = (float*)(ws + OFF_MENC);
  float* biasE = (float*)(ws + OFF_BIASE);
  float* xpv   = (float*)(ws + OFF_XPV);
  unsigned int* flags = (unsigned int*)(ws + OFF_FLAGS);
  unsigned short* hx  = (unsigned short*)(ws + OFF_HX);
  float* hfin = (float*)(ws + OFF_HFIN);
  float* qbuf = (float*)(ws + OFF_QBUF);
  float* ubuf = (float*)(ws + OFF_UBUF);

  hipLaunchKernelGGL(k0_prep, dim3(256), dim3(256), 0, stream,
                     eWih, eWhh, ebih, ebhh, pWih, pWhh, pbih, pbhh, W_emb, dec_in,
                     Wref, WhhE, WhhP, Wrefb, Menc, biasE, xpv, flags, ubuf);
  hipLaunchKernelGGL(k1_lstm, dim3(32), dim3(512), 0, stream,
                     inp, WhhE, WhhP, Menc, biasE, xpv, enc_out, hx, flags, hfin);
  hipLaunchKernelGGL(k1b_q, dim3(256), dim3(256), 0, stream, hfin, Wq, bq, qbuf);
  hipLaunchKernelGGL(k2_att, dim3(2048), dim3(512), 0, stream,
                     enc_out, Wrefb, qbuf, bref, V, ubuf);
  hipLaunchKernelGGL(k3_head, dim3(256), dim3(256), 0, stream,
                     ubuf, enc_out, Wd1, Wd2, out);
}

// Round 7
// 3817.069 us; speedup vs baseline: 2.1724x; 1.0126x over previous
//
#include <hip/hip_runtime.h>

#define B_ 256
#define S_ 512
#define E_ 128
#define H_ 256
#define FH_ 1024
#define HROW 264  // 256 + 8 pad (shorts) -> row offset 132 dwords = 4 mod 32, conflict-free

typedef __bf16 bf16x8 __attribute__((ext_vector_type(8)));
typedef float f32x4 __attribute__((ext_vector_type(4)));
typedef unsigned short u16x4 __attribute__((ext_vector_type(4)));
typedef unsigned short u16x8 __attribute__((ext_vector_type(8)));

__device__ __forceinline__ unsigned short f2bf(float f) {
  union { float f; unsigned int u; } a; a.f = f;
  unsigned int u = a.u;
  u += 0x7fffu + ((u >> 16) & 1u);  // RNE
  return (unsigned short)(u >> 16);
}
__device__ __forceinline__ float bf2f(unsigned short v) {
  union { unsigned int u; float f; } a; a.u = ((unsigned int)v) << 16;
  return a.f;
}
__device__ __forceinline__ float sigm(float x) { return 1.f / (1.f + __expf(-x)); }
__device__ __forceinline__ float tanh_(float x) {
  float e = __expf(2.f * x);
  return 1.f - 2.f / (e + 1.f);
}

// ---------------- workspace layout (bytes) ----------------
#define OFF_ENC    ((size_t)0)          // enc_out bf16 [256][512][256]  67108864
#define OFF_WHHE   ((size_t)67108864)   // enc_Whh bf16 [1024][256]        524288
#define OFF_WHHP   ((size_t)67633152)   // pb_Whh  bf16                    524288
#define OFF_WREF   ((size_t)68157440)   // Wref    bf16 [256][256]         131072
#define OFF_MENC   ((size_t)68288512)   // M = enc_Wih@W_emb f32 [1024][2]   8192
#define OFF_BIASE  ((size_t)68296704)   // enc_bih+enc_bhh f32 [1024]        4096
#define OFF_XPV    ((size_t)68300800)   // pb x-projection f32 [1024]        4096
#define OFF_FLAGS  ((size_t)68304896)   // u32 flags                         1024
#define OFF_HX     ((size_t)68305920)   // h exchange bf16 [2][16][2][16][128] 262144
#define OFF_HFIN   ((size_t)68568064)   // final h f32 [256][256]          262144
#define OFF_QBUF   ((size_t)68830208)   // q f32 [256][256]                262144
#define OFF_UBUF   ((size_t)69092352)   // u f32 [256][512]                524288

// ---------------- K0: prep (weight conversion, folded projections, zeroing) ----
__global__ void k0_prep(const float* __restrict__ eWih, const float* __restrict__ eWhh,
                        const float* __restrict__ ebih, const float* __restrict__ ebhh,
                        const float* __restrict__ pWih, const float* __restrict__ pWhh,
                        const float* __restrict__ pbih, const float* __restrict__ pbhh,
                        const float* __restrict__ W_emb, const float* __restrict__ dec_in,
                        const float* __restrict__ Wref,
                        unsigned short* __restrict__ WhhE, unsigned short* __restrict__ WhhP,
                        unsigned short* __restrict__ Wrefb,
                        float* __restrict__ Menc, float* __restrict__ biasE,
                        float* __restrict__ xpv,
                        unsigned int* __restrict__ flags, float* __restrict__ ubuf) {
  int gid = blockIdx.x * blockDim.x + threadIdx.x;
  int NT = gridDim.x * blockDim.x;
  for (int i = gid; i < FH_ * H_; i += NT) {
    WhhE[i] = f2bf(eWhh[i]);
    WhhP[i] = f2bf(pWhh[i]);
  }
  for (int i = gid; i < H_ * H_; i += NT) Wrefb[i] = f2bf(Wref[i]);
  for (int i = gid; i < B_ * S_; i += NT) ubuf[i] = 0.f;
  if (gid < 256) flags[gid] = 0u;
  if (gid < FH_) {
    int n = gid;
    float m0 = 0.f, m1 = 0.f, xs = 0.f;
    for (int e = 0; e < E_; ++e) {
      float w = eWih[n * E_ + e];
      m0 += w * W_emb[e * 2 + 0];
      m1 += w * W_emb[e * 2 + 1];
      xs += pWih[n * E_ + e] * dec_in[e];
    }
    Menc[n * 2 + 0] = m0;
    Menc[n * 2 + 1] = m1;
    biasE[n] = ebih[n] + ebhh[n];
    xpv[n] = xs + pbih[n] + pbhh[n];
  }
}

// ---------------- K1: persistent dual-LSTM recurrence ----------------
// 32 WGs x 512 threads (proven R2/R3 structure). Pair of WGs (halves) split
// the 1024 gate columns; each WG's Whh half slice (512B/thread = 128 VGPRs)
// register-resident.
// WHY THE ASM PIN: the per-step agent-scope ACQUIRE is a memory fence, so the
// compiler may not hoist the weight loads across it -- it re-loaded 512B/thr
// every step in rounds 0-3 and 6 (VGPR_Count 108-120, FETCH_SIZE ~6 GB
// = 512B x threads x steps) regardless of launch bounds / volatile / naming.
// Laundering the loaded values through an empty asm makes them opaque
// register values that CANNOT be rematerialized from memory; with
// waves_per_eu(2,2) the budget is 256 regs so they cannot be spilled either.
// Handshake: byte-identical proven release/acquire protocol.
__launch_bounds__(512)
__attribute__((amdgpu_waves_per_eu(2, 2)))
__global__ void k1_lstm(const float* __restrict__ inp,
                        const unsigned short* __restrict__ WhhE,
                        const unsigned short* __restrict__ WhhP,
                        const float* __restrict__ Menc, const float* __restrict__ biasE,
                        const float* __restrict__ xpv,
                        unsigned short* __restrict__ enc_out,
                        unsigned short* __restrict__ hx,
                        unsigned int* __restrict__ flags,
                        float* __restrict__ hfin) {
  __shared__ unsigned short hbuf[16 * HROW];  // h bf16, 16 rows x (256+pad)
  __shared__ float xin[16][2];
  const int tid = threadIdx.x;
  const int wave = tid >> 6, lane = tid & 63, quad = lane >> 4, l16 = lane & 15;
  const int blk = blockIdx.x;
  const int grp = (blk & 7) | ((blk >> 4) << 3);  // 0..15
  const int half = (blk >> 3) & 1;
  const int kloc = (wave << 4) | l16;    // 0..127 within half
  const int kcol = half * 128 + kloc;    // 0..255 global h-column

  for (int i = tid; i < 16 * HROW; i += 512) hbuf[i] = 0;
  if (tid < 32) xin[tid >> 1][tid & 1] = inp[((grp * 16 + (tid >> 1)) * S_ + 0) * 2 + (tid & 1)];

  float c[4] = {0.f, 0.f, 0.f, 0.f};
  float hreg[4] = {0.f, 0.f, 0.f, 0.f};
  // 32 named weight fragments (4 gates x 8 k-chunks), 128 VGPRs total.
  // Stored as f32x4 (bit-identical 16B); cast to bf16x8 at the MFMA.
  f32x4 W00, W01, W02, W03, W04, W05, W06, W07;
  f32x4 W10, W11, W12, W13, W14, W15, W16, W17;
  f32x4 W20, W21, W22, W23, W24, W25, W26, W27;
  f32x4 W30, W31, W32, W33, W34, W35, W36, W37;
  float m0c[4], m1c[4], bc[4];
  unsigned int* myflag = flags + grp * 2 + half;
  unsigned int* pflag = flags + grp * 2 + (1 - half);
  const f32x4 z4 = {0.f, 0.f, 0.f, 0.f};
  __syncthreads();

  int t = 0;
#pragma unroll 1
  for (int phase = 0; phase < 2; ++phase) {
    const unsigned short* W = phase ? WhhP : WhhE;
#define WLOAD(g)                                                        \
    {                                                                   \
      const unsigned short* wp = W + (g * 256 + kcol) * H_ + quad * 8;  \
      W##g##0 = *(const f32x4*)(wp + 0 * 32);                           \
      W##g##1 = *(const f32x4*)(wp + 1 * 32);                           \
      W##g##2 = *(const f32x4*)(wp + 2 * 32);                           \
      W##g##3 = *(const f32x4*)(wp + 3 * 32);                           \
      W##g##4 = *(const f32x4*)(wp + 4 * 32);                           \
      W##g##5 = *(const f32x4*)(wp + 5 * 32);                           \
      W##g##6 = *(const f32x4*)(wp + 6 * 32);                           \
      W##g##7 = *(const f32x4*)(wp + 7 * 32);                           \
    }
    WLOAD(0) WLOAD(1) WLOAD(2) WLOAD(3)
#undef WLOAD
    // Launder: values become opaque asm results -> cannot be re-loaded from
    // memory by the compiler, must stay in VGPRs across the step loop.
    asm volatile(""
                 : "+v"(W00), "+v"(W01), "+v"(W02), "+v"(W03),
                   "+v"(W04), "+v"(W05), "+v"(W06), "+v"(W07),
                   "+v"(W10), "+v"(W11), "+v"(W12), "+v"(W13),
                   "+v"(W14), "+v"(W15), "+v"(W16), "+v"(W17),
                   "+v"(W20), "+v"(W21), "+v"(W22), "+v"(W23),
                   "+v"(W24), "+v"(W25), "+v"(W26), "+v"(W27),
                   "+v"(W30), "+v"(W31), "+v"(W32), "+v"(W33),
                   "+v"(W34), "+v"(W35), "+v"(W36), "+v"(W37));
#pragma unroll
    for (int gg = 0; gg < 4; ++gg) {
      int n = gg * 256 + kcol;
      if (phase == 0) {
        m0c[gg] = Menc[n * 2 + 0]; m1c[gg] = Menc[n * 2 + 1]; bc[gg] = biasE[n];
      } else {
        m0c[gg] = 0.f; m1c[gg] = 0.f; bc[gg] = xpv[n];
      }
    }
#pragma unroll 1
    for (int step = 0; step < 512; ++step, ++t) {
      // ---- GEMM: g = h @ Whh^T (this WG's 512 columns) ----
      f32x4 acc0 = z4, acc1 = z4, acc2 = z4, acc3 = z4;
#define MSTEP(kt)                                                              \
      {                                                                        \
        bf16x8 Af = *(const bf16x8*)(hbuf + l16 * HROW + kt * 32 + quad * 8);  \
        acc0 = __builtin_amdgcn_mfma_f32_16x16x32_bf16(                        \
            Af, __builtin_bit_cast(bf16x8, W0##kt), acc0, 0, 0, 0);            \
        acc1 = __builtin_amdgcn_mfma_f32_16x16x32_bf16(                        \
            Af, __builtin_bit_cast(bf16x8, W1##kt), acc1, 0, 0, 0);            \
        acc2 = __builtin_amdgcn_mfma_f32_16x16x32_bf16(                        \
            Af, __builtin_bit_cast(bf16x8, W2##kt), acc2, 0, 0, 0);            \
        acc3 = __builtin_amdgcn_mfma_f32_16x16x32_bf16(                        \
            Af, __builtin_bit_cast(bf16x8, W3##kt), acc3, 0, 0, 0);            \
      }
      MSTEP(0) MSTEP(1) MSTEP(2) MSTEP(3) MSTEP(4) MSTEP(5) MSTEP(6) MSTEP(7)
#undef MSTEP
      // ---- gates (fp32). lane holds rows quad*4+r, column kcol, all 4 gates ----
      unsigned short hb[4];
#pragma unroll
      for (int r = 0; r < 4; ++r) {
        int bl = quad * 4 + r;
        float x0 = xin[bl][0], x1 = xin[bl][1];
        float gi = acc0[r] + x0 * m0c[0] + x1 * m1c[0] + bc[0];
        float gf = acc1[r] + x0 * m0c[1] + x1 * m1c[1] + bc[1];
        float gc = acc2[r] + x0 * m0c[2] + x1 * m1c[2] + bc[2];
        float go = acc3[r] + x0 * m0c[3] + x1 * m1c[3] + bc[3];
        float cn = sigm(gf) * c[r] + sigm(gi) * tanh_(gc);
        c[r] = cn;
        hreg[r] = sigm(go) * tanh_(cn);
        hb[r] = f2bf(hreg[r]);
      }
      // ---- publish own half (global) ----
      if (phase == 0) {
#pragma unroll
        for (int r = 0; r < 4; ++r)
          enc_out[(((size_t)(grp * 16 + quad * 4 + r) * S_ + step)) * H_ + kcol] = hb[r];
      }
      {
        unsigned short* hxs = hx + ((size_t)((t & 1) * 32 + grp * 2 + half)) * 2048;
#pragma unroll
        for (int r = 0; r < 4; ++r) hxs[(quad * 4 + r) * 128 + kloc] = hb[r];
      }
      __syncthreads();  // (a) A-frag reads done; hx stores drained
      if (tid == 0) {
        __hip_atomic_store(myflag, (unsigned int)(t + 1), __ATOMIC_RELEASE,
                           __HIP_MEMORY_SCOPE_AGENT);
        while (__hip_atomic_load(pflag, __ATOMIC_ACQUIRE, __HIP_MEMORY_SCOPE_AGENT) <
               (unsigned int)(t + 1)) {
          __builtin_amdgcn_s_sleep(1);
        }
      }
      __syncthreads();  // (b)
      // ---- update LDS h: own half from regs, peer half from hx ----
#pragma unroll
      for (int r = 0; r < 4; ++r) hbuf[(quad * 4 + r) * HROW + kcol] = hb[r];
      {
        const unsigned short* ph = hx + ((size_t)((t & 1) * 32 + grp * 2 + (1 - half))) * 2048;
        int idx = tid * 4;  // 0..2047
        int prow = idx >> 7, pcol = idx & 127;
        u16x4 v = *(const u16x4*)(ph + idx);
        *(u16x4*)(hbuf + prow * HROW + (1 - half) * 128 + pcol) = v;
      }
      if (phase == 0 && step < 511 && tid < 32)
        xin[tid >> 1][tid & 1] =
            inp[((grp * 16 + (tid >> 1)) * S_ + (step + 1)) * 2 + (tid & 1)];
      __syncthreads();  // (c) h ready for next step
    }
  }
  // final h (fp32) for the attention query
#pragma unroll
  for (int r = 0; r < 4; ++r)
    hfin[(grp * 16 + quad * 4 + r) * H_ + kcol] = hreg[r];
}

// ---------------- K1b: q = h @ Wq^T + bq (fp32) ----------------
__global__ void k1b_q(const float* __restrict__ hfin, const float* __restrict__ Wq,
                      const float* __restrict__ bq, float* __restrict__ qbuf) {
  __shared__ float hl[H_];
  int b = blockIdx.x, j = threadIdx.x;
  hl[j] = hfin[b * H_ + j];
  __syncthreads();
  float s = bq[j];
  const float* w = Wq + j * H_;
  for (int k = 0; k < H_; ++k) s += hl[k] * w[k];
  qbuf[b * H_ + j] = s;
}

// ---------------- K2: u = tanh(enc_out@Wref^T + bref + q) @ V (fused) ----------
__launch_bounds__(512)
__global__ void k2_att(const unsigned short* __restrict__ enc_out,
                       const unsigned short* __restrict__ Wrefb,
                       const float* __restrict__ qbuf, const float* __restrict__ bref,
                       const float* __restrict__ V, float* __restrict__ ubuf) {
  __shared__ unsigned short Bs[128 * HROW];
  __shared__ float qs[128], Vs[128];
  int tid = threadIdx.x;
  int wave = tid >> 6, lane = tid & 63, quad = lane >> 4, l16 = lane & 15;
  int rowblk = blockIdx.x >> 1, nb = blockIdx.x & 1;
  int b = rowblk >> 2;
  {  // stage Wref block [nb*128 .. +128) x 256 into LDS
    int nl = tid >> 2, seg = tid & 3;
    const unsigned short* src = Wrefb + (nb * 128 + nl) * H_ + seg * 64;
    unsigned short* dst = Bs + nl * HROW + seg * 64;
#pragma unroll
    for (int i = 0; i < 8; ++i) *(u16x8*)(dst + i * 8) = *(const u16x8*)(src + i * 8);
  }
  if (tid < 128) {
    int j = nb * 128 + tid;
    qs[tid] = qbuf[b * H_ + j] + bref[j];
    Vs[tid] = V[j];
  }
  __syncthreads();
  int rw = rowblk * 128 + wave * 16 + l16;  // global (b,s) row
  const f32x4 z4 = {0.f, 0.f, 0.f, 0.f};
  f32x4 acc[8];
#pragma unroll
  for (int kt = 0; kt < 8; ++kt) {
    bf16x8 af = *(const bf16x8*)(enc_out + (size_t)rw * H_ + kt * 32 + quad * 8);
#pragma unroll
    for (int nt = 0; nt < 8; ++nt) {
      bf16x8 bfr = *(const bf16x8*)(Bs + (nt * 16 + l16) * HROW + kt * 32 + quad * 8);
      acc[nt] = __builtin_amdgcn_mfma_f32_16x16x32_bf16(af, bfr, (kt == 0) ? z4 : acc[nt],
                                                        0, 0, 0);
    }
  }
  float part[4] = {0.f, 0.f, 0.f, 0.f};
#pragma unroll
  for (int nt = 0; nt < 8; ++nt) {
    float qv = qs[nt * 16 + l16], vv = Vs[nt * 16 + l16];
#pragma unroll
    for (int r = 0; r < 4; ++r) part[r] += tanh_(acc[nt][r] + qv) * vv;
  }
#pragma unroll
  for (int m = 1; m < 16; m <<= 1) {
#pragma unroll
    for (int r = 0; r < 4; ++r) part[r] += __shfl_xor(part[r], m, 64);
  }
  if (l16 == 0) {
    int s0 = (rowblk & 3) * 128 + wave * 16 + quad * 4;
#pragma unroll
    for (int r = 0; r < 4; ++r) atomicAdd(&ubuf[b * S_ + s0 + r], part[r]);
  }
}

// ---------------- K3: softmax + glimpse + decoder head ----------------
__global__ void k3_head(const float* __restrict__ ubuf,
                        const unsigned short* __restrict__ enc_out,
                        const float* __restrict__ Wd1, const float* __restrict__ Wd2,
                        float* __restrict__ out) {
  __shared__ float sm[512];
  __shared__ float red[256];
  __shared__ float gl[256];
  int b = blockIdx.x, tid = threadIdx.x;
  float u0 = ubuf[b * S_ + tid], u1 = ubuf[b * S_ + 256 + tid];
  red[tid] = fmaxf(u0, u1);
  __syncthreads();
  for (int s = 128; s > 0; s >>= 1) {
    if (tid < s) red[tid] = fmaxf(red[tid], red[tid + s]);
    __syncthreads();
  }
  float mx = red[0];
  __syncthreads();
  float e0 = __expf(u0 - mx), e1 = __expf(u1 - mx);
  red[tid] = e0 + e1;
  __syncthreads();
  for (int s = 128; s > 0; s >>= 1) {
    if (tid < s) red[tid] += red[tid + s];
    __syncthreads();
  }
  float inv = 1.f / red[0];
  sm[tid] = e0 * inv;
  sm[256 + tid] = e1 * inv;
  __syncthreads();
  float g = 0.f;
  const unsigned short* eo = enc_out + (size_t)b * S_ * H_ + tid;
  for (int s = 0; s < S_; ++s) g += sm[s] * bf2f(eo[(size_t)s * H_]);
  gl[tid] = g;
  __syncthreads();
  float y = 0.f;
  const float* w = Wd1 + tid * H_;
  for (int j = 0; j < H_; ++j) y += w[j] * gl[j];
  y = fmaxf(y, 0.f) * Wd2[tid];
  red[tid] = y;
  __syncthreads();
  for (int s = 128; s > 0; s >>= 1) {
    if (tid < s) red[tid] += red[tid + s];
    __syncthreads();
  }
  if (tid == 0) out[b] = red[0];
}

extern "C" void kernel_launch(void* const* d_in, const int* in_sizes, int n_in,
                              void* d_out, int out_size, void* d_ws, size_t ws_size,
                              hipStream_t stream) {
  (void)in_sizes; (void)n_in; (void)out_size; (void)ws_size;
  const float* inp    = (const float*)d_in[0];
  const float* W_emb  = (const float*)d_in[1];
  const float* dec_in = (const float*)d_in[2];
  const float* eWih   = (const float*)d_in[3];
  const float* eWhh   = (const float*)d_in[4];
  const float* ebih   = (const float*)d_in[5];
  const float* ebhh   = (const float*)d_in[6];
  const float* pWih   = (const float*)d_in[7];
  const float* pWhh   = (const float*)d_in[8];
  const float* pbih   = (const float*)d_in[9];
  const float* pbhh   = (const float*)d_in[10];
  const float* Wq     = (const float*)d_in[11];
  const float* bq     = (const float*)d_in[12];
  const float* Wref   = (const float*)d_in[13];
  const float* bref   = (const float*)d_in[14];
  const float* V      = (const float*)d_in[15];
  const float* Wd1    = (const float*)d_in[16];
  const float* Wd2    = (const float*)d_in[17];
  float* out = (float*)d_out;

  char* ws = (char*)d_ws;
  unsigned short* enc_out = (unsigned short*)(ws + OFF_ENC);
  unsigned short* WhhE    = (unsigned short*)(ws + OFF_WHHE);
  unsigned short* WhhP    = (unsigned short*)(ws + OFF_WHHP);
  unsigned short* Wrefb   = (unsigned short*)(ws + OFF_WREF);
  float* Menc  = (float*)(ws + OFF_MENC);
  float* biasE = (float*)(ws + OFF_BIASE);
  float* xpv   = (float*)(ws + OFF_XPV);
  unsigned int* flags = (unsigned int*)(ws + OFF_FLAGS);
  unsigned short* hx  = (unsigned short*)(ws + OFF_HX);
  float* hfin = (float*)(ws + OFF_HFIN);
  float* qbuf = (float*)(ws + OFF_QBUF);
  float* ubuf = (float*)(ws + OFF_UBUF);

  hipLaunchKernelGGL(k0_prep, dim3(256), dim3(256), 0, stream,
                     eWih, eWhh, ebih, ebhh, pWih, pWhh, pbih, pbhh, W_emb, dec_in,
                     Wref, WhhE, WhhP, Wrefb, Menc, biasE, xpv, flags, ubuf);
  hipLaunchKernelGGL(k1_lstm, dim3(32), dim3(512), 0, stream,
                     inp, WhhE, WhhP, Menc, biasE, xpv, enc_out, hx, flags, hfin);
  hipLaunchKernelGGL(k1b_q, dim3(256), dim3(256), 0, stream, hfin, Wq, bq, qbuf);
  hipLaunchKernelGGL(k2_att, dim3(2048), dim3(512), 0, stream,
                     enc_out, Wrefb, qbuf, bref, V, ubuf);
  hipLaunchKernelGGL(k3_head, dim3(256), dim3(256), 0, stream,
                     ubuf, enc_out, Wd1, Wd2, out);
}

// Round 8
// 3224.169 us; speedup vs baseline: 2.5719x; 1.1839x over previous
//
#include <hip/hip_runtime.h>

#define B_ 256
#define S_ 512
#define E_ 128
#define H_ 256
#define FH_ 1024
#define HROW 264  // 256 + 8 pad (shorts) -> row offset 132 dwords = 4 mod 32, conflict-free

typedef __bf16 bf16x8 __attribute__((ext_vector_type(8)));
typedef float f32x4 __attribute__((ext_vector_type(4)));
typedef unsigned short u16x4 __attribute__((ext_vector_type(4)));
typedef unsigned short u16x8 __attribute__((ext_vector_type(8)));

__device__ __forceinline__ unsigned short f2bf(float f) {
  union { float f; unsigned int u; } a; a.f = f;
  unsigned int u = a.u;
  u += 0x7fffu + ((u >> 16) & 1u);  // RNE
  return (unsigned short)(u >> 16);
}
__device__ __forceinline__ float bf2f(unsigned short v) {
  union { unsigned int u; float f; } a; a.u = ((unsigned int)v) << 16;
  return a.f;
}
__device__ __forceinline__ float sigm(float x) { return 1.f / (1.f + __expf(-x)); }
__device__ __forceinline__ float tanh_(float x) {
  float e = __expf(2.f * x);
  return 1.f - 2.f / (e + 1.f);
}

// ---------------- workspace layout (bytes) ----------------
#define OFF_ENC    ((size_t)0)          // enc_out bf16 [256][512][256]  67108864
#define OFF_WHHE   ((size_t)67108864)   // enc_Whh bf16 [1024][256]        524288
#define OFF_WHHP   ((size_t)67633152)   // pb_Whh  bf16                    524288
#define OFF_WREF   ((size_t)68157440)   // Wref    bf16 [256][256]         131072
#define OFF_MENC   ((size_t)68288512)   // M = enc_Wih@W_emb f32 [1024][2]   8192
#define OFF_BIASE  ((size_t)68296704)   // enc_bih+enc_bhh f32 [1024]        4096
#define OFF_XPV    ((size_t)68300800)   // pb x-projection f32 [1024]        4096
#define OFF_FLAGS  ((size_t)68304896)   // u32 flags                         1024
#define OFF_HX     ((size_t)68305920)   // h exchange bf16 [2][16][2][128][16] 262144
#define OFF_HFIN   ((size_t)68568064)   // final h f32 [256][256]          262144
#define OFF_QBUF   ((size_t)68830208)   // q f32 [256][256]                262144
#define OFF_UBUF   ((size_t)69092352)   // u f32 [256][512]                524288

// ---------------- K0: prep (weight conversion, folded projections, zeroing) ----
__global__ void k0_prep(const float* __restrict__ eWih, const float* __restrict__ eWhh,
                        const float* __restrict__ ebih, const float* __restrict__ ebhh,
                        const float* __restrict__ pWih, const float* __restrict__ pWhh,
                        const float* __restrict__ pbih, const float* __restrict__ pbhh,
                        const float* __restrict__ W_emb, const float* __restrict__ dec_in,
                        const float* __restrict__ Wref,
                        unsigned short* __restrict__ WhhE, unsigned short* __restrict__ WhhP,
                        unsigned short* __restrict__ Wrefb,
                        float* __restrict__ Menc, float* __restrict__ biasE,
                        float* __restrict__ xpv,
                        unsigned int* __restrict__ flags, float* __restrict__ ubuf) {
  int gid = blockIdx.x * blockDim.x + threadIdx.x;
  int NT = gridDim.x * blockDim.x;
  for (int i = gid; i < FH_ * H_; i += NT) {
    WhhE[i] = f2bf(eWhh[i]);
    WhhP[i] = f2bf(pWhh[i]);
  }
  for (int i = gid; i < H_ * H_; i += NT) Wrefb[i] = f2bf(Wref[i]);
  for (int i = gid; i < B_ * S_; i += NT) ubuf[i] = 0.f;
  if (gid < 256) flags[gid] = 0u;
  if (gid < FH_) {
    int n = gid;
    float m0 = 0.f, m1 = 0.f, xs = 0.f;
    for (int e = 0; e < E_; ++e) {
      float w = eWih[n * E_ + e];
      m0 += w * W_emb[e * 2 + 0];
      m1 += w * W_emb[e * 2 + 1];
      xs += pWih[n * E_ + e] * dec_in[e];
    }
    Menc[n * 2 + 0] = m0;
    Menc[n * 2 + 1] = m1;
    biasE[n] = ebih[n] + ebhh[n];
    xpv[n] = xs + pbih[n] + pbhh[n];
  }
}

// ---------------- K1: persistent dual-LSTM recurrence ----------------
// 32 WGs x 512 threads (proven structure). Pair of WGs (halves) split the
// 1024 gate columns.
// ERRATA driving this round: FETCH_SIZE is KB -- the kernel reads ~6 MB, not
// GB. It was NEVER bandwidth-bound. The 8800-cy step is LATENCY from the
// agent-scope release/acquire: RELEASE = buffer_wbl2 (write back + drain the
// XCD's L2), each ACQUIRE poll = buffer_inv (invalidate the XCD's L2).
// FIX: RELAXED agent-scope atomics only. Relaxed agent atomics execute at the
// coherence point (L3, cross-XCD atomic) but emit NO wbl2/inv. Ordering:
//   hx stores (8B relaxed atomics) -> bar(a) [syncthreads drains vmcnt(0),
//   stores landed at L3] -> tid0 flag store (relaxed)
//   peer tid0 spins flag (relaxed, reads L3) -> bar(b) -> threads load hx
//   (8B relaxed atomics, bypass stale L2, hit L3).
// Correct for any WG->XCD placement; (blk, blk+8) pairing is perf-only.
__launch_bounds__(512)
__attribute__((amdgpu_waves_per_eu(2, 2)))
__global__ void k1_lstm(const float* __restrict__ inp,
                        const unsigned short* __restrict__ WhhE,
                        const unsigned short* __restrict__ WhhP,
                        const float* __restrict__ Menc, const float* __restrict__ biasE,
                        const float* __restrict__ xpv,
                        unsigned short* __restrict__ enc_out,
                        unsigned short* __restrict__ hx,
                        unsigned int* __restrict__ flags,
                        float* __restrict__ hfin) {
  __shared__ unsigned short hbuf[16 * HROW];  // h bf16, 16 rows x (256+pad)
  __shared__ float xin[16][2];
  const int tid = threadIdx.x;
  const int wave = tid >> 6, lane = tid & 63, quad = lane >> 4, l16 = lane & 15;
  const int blk = blockIdx.x;
  const int grp = (blk & 7) | ((blk >> 4) << 3);  // 0..15
  const int half = (blk >> 3) & 1;
  const int kloc = (wave << 4) | l16;    // 0..127 within half
  const int kcol = half * 128 + kloc;    // 0..255 global h-column

  for (int i = tid; i < 16 * HROW; i += 512) hbuf[i] = 0;
  if (tid < 32) xin[tid >> 1][tid & 1] = inp[((grp * 16 + (tid >> 1)) * S_ + 0) * 2 + (tid & 1)];

  float c[4] = {0.f, 0.f, 0.f, 0.f};
  float hreg[4] = {0.f, 0.f, 0.f, 0.f};
  // 32 named weight fragments (4 gates x 8 k-chunks), 128 VGPRs target.
  f32x4 W00, W01, W02, W03, W04, W05, W06, W07;
  f32x4 W10, W11, W12, W13, W14, W15, W16, W17;
  f32x4 W20, W21, W22, W23, W24, W25, W26, W27;
  f32x4 W30, W31, W32, W33, W34, W35, W36, W37;
  float m0c[4], m1c[4], bc[4];
  unsigned int* myflag = flags + grp * 2 + half;
  unsigned int* pflag = flags + grp * 2 + (1 - half);
  const f32x4 z4 = {0.f, 0.f, 0.f, 0.f};
  __syncthreads();

  int t = 0;
#pragma unroll 1
  for (int phase = 0; phase < 2; ++phase) {
    const unsigned short* W = phase ? WhhP : WhhE;
#define WLOAD(g)                                                        \
    {                                                                   \
      const unsigned short* wp = W + (g * 256 + kcol) * H_ + quad * 8;  \
      W##g##0 = *(const f32x4*)(wp + 0 * 32);                           \
      W##g##1 = *(const f32x4*)(wp + 1 * 32);                           \
      W##g##2 = *(const f32x4*)(wp + 2 * 32);                           \
      W##g##3 = *(const f32x4*)(wp + 3 * 32);                           \
      W##g##4 = *(const f32x4*)(wp + 4 * 32);                           \
      W##g##5 = *(const f32x4*)(wp + 5 * 32);                           \
      W##g##6 = *(const f32x4*)(wp + 6 * 32);                           \
      W##g##7 = *(const f32x4*)(wp + 7 * 32);                           \
    }
    WLOAD(0) WLOAD(1) WLOAD(2) WLOAD(3)
#undef WLOAD
    asm volatile(""
                 : "+v"(W00), "+v"(W01), "+v"(W02), "+v"(W03),
                   "+v"(W04), "+v"(W05), "+v"(W06), "+v"(W07),
                   "+v"(W10), "+v"(W11), "+v"(W12), "+v"(W13),
                   "+v"(W14), "+v"(W15), "+v"(W16), "+v"(W17),
                   "+v"(W20), "+v"(W21), "+v"(W22), "+v"(W23),
                   "+v"(W24), "+v"(W25), "+v"(W26), "+v"(W27),
                   "+v"(W30), "+v"(W31), "+v"(W32), "+v"(W33),
                   "+v"(W34), "+v"(W35), "+v"(W36), "+v"(W37));
#pragma unroll
    for (int gg = 0; gg < 4; ++gg) {
      int n = gg * 256 + kcol;
      if (phase == 0) {
        m0c[gg] = Menc[n * 2 + 0]; m1c[gg] = Menc[n * 2 + 1]; bc[gg] = biasE[n];
      } else {
        m0c[gg] = 0.f; m1c[gg] = 0.f; bc[gg] = xpv[n];
      }
    }
#pragma unroll 1
    for (int step = 0; step < 512; ++step, ++t) {
      // ---- prefetch next step's x (latency hidden under GEMM) ----
      float xpre = 0.f;
      if (phase == 0 && tid < 32) {
        int sN = (step < 511) ? step + 1 : 511;
        xpre = inp[((grp * 16 + (tid >> 1)) * S_ + sN) * 2 + (tid & 1)];
      }
      // ---- GEMM: g = h @ Whh^T (this WG's 512 columns) ----
      f32x4 acc0 = z4, acc1 = z4, acc2 = z4, acc3 = z4;
#define MSTEP(kt)                                                              \
      {                                                                        \
        bf16x8 Af = *(const bf16x8*)(hbuf + l16 * HROW + kt * 32 + quad * 8);  \
        acc0 = __builtin_amdgcn_mfma_f32_16x16x32_bf16(                        \
            Af, __builtin_bit_cast(bf16x8, W0##kt), acc0, 0, 0, 0);            \
        acc1 = __builtin_amdgcn_mfma_f32_16x16x32_bf16(                        \
            Af, __builtin_bit_cast(bf16x8, W1##kt), acc1, 0, 0, 0);            \
        acc2 = __builtin_amdgcn_mfma_f32_16x16x32_bf16(                        \
            Af, __builtin_bit_cast(bf16x8, W2##kt), acc2, 0, 0, 0);            \
        acc3 = __builtin_amdgcn_mfma_f32_16x16x32_bf16(                        \
            Af, __builtin_bit_cast(bf16x8, W3##kt), acc3, 0, 0, 0);            \
      }
      MSTEP(0) MSTEP(1) MSTEP(2) MSTEP(3) MSTEP(4) MSTEP(5) MSTEP(6) MSTEP(7)
#undef MSTEP
      // ---- gates (fp32). lane holds rows quad*4+r, column kcol, all 4 gates ----
      unsigned short hb[4];
#pragma unroll
      for (int r = 0; r < 4; ++r) {
        int bl = quad * 4 + r;
        float x0 = xin[bl][0], x1 = xin[bl][1];
        float gi = acc0[r] + x0 * m0c[0] + x1 * m1c[0] + bc[0];
        float gf = acc1[r] + x0 * m0c[1] + x1 * m1c[1] + bc[1];
        float gc = acc2[r] + x0 * m0c[2] + x1 * m1c[2] + bc[2];
        float go = acc3[r] + x0 * m0c[3] + x1 * m1c[3] + bc[3];
        float cn = sigm(gf) * c[r] + sigm(gi) * tanh_(gc);
        c[r] = cn;
        hreg[r] = sigm(go) * tanh_(cn);
        hb[r] = f2bf(hreg[r]);
      }
      // ---- publish own half (global) ----
      if (phase == 0) {
#pragma unroll
        for (int r = 0; r < 4; ++r)
          enc_out[(((size_t)(grp * 16 + quad * 4 + r) * S_ + step)) * H_ + kcol] = hb[r];
      }
      {  // one packed 8B relaxed agent atomic; layout [kloc][row]
        unsigned short* hxs = hx + ((size_t)((t & 1) * 32 + grp * 2 + half)) * 2048;
        unsigned long long pack = (unsigned long long)hb[0] |
                                  ((unsigned long long)hb[1] << 16) |
                                  ((unsigned long long)hb[2] << 32) |
                                  ((unsigned long long)hb[3] << 48);
        __hip_atomic_store((unsigned long long*)(hxs + kloc * 16 + quad * 4), pack,
                           __ATOMIC_RELAXED, __HIP_MEMORY_SCOPE_AGENT);
      }
      __syncthreads();  // (a) hbuf/xin reads done; hx stores drained to L3 (vmcnt0)
      if (phase == 0 && tid < 32) xin[tid >> 1][tid & 1] = xpre;
      if (tid == 0) {
        __hip_atomic_store(myflag, (unsigned int)(t + 1), __ATOMIC_RELAXED,
                           __HIP_MEMORY_SCOPE_AGENT);
        while (__hip_atomic_load(pflag, __ATOMIC_RELAXED, __HIP_MEMORY_SCOPE_AGENT) <
               (unsigned int)(t + 1)) {
          __builtin_amdgcn_s_sleep(1);
        }
      }
      __syncthreads();  // (b)
      // ---- update LDS h: own half from regs, peer half from hx ----
#pragma unroll
      for (int r = 0; r < 4; ++r) hbuf[(quad * 4 + r) * HROW + kcol] = hb[r];
      {
        const unsigned short* ph = hx + ((size_t)((t & 1) * 32 + grp * 2 + (1 - half))) * 2048;
        unsigned long long pv = __hip_atomic_load(
            (const unsigned long long*)(ph + tid * 4), __ATOMIC_RELAXED,
            __HIP_MEMORY_SCOPE_AGENT);
        int kp = tid >> 2, r0 = (tid & 3) * 4;
        unsigned short* dst = hbuf + (1 - half) * 128 + kp;
        dst[(size_t)(r0 + 0) * HROW] = (unsigned short)(pv);
        dst[(size_t)(r0 + 1) * HROW] = (unsigned short)(pv >> 16);
        dst[(size_t)(r0 + 2) * HROW] = (unsigned short)(pv >> 32);
        dst[(size_t)(r0 + 3) * HROW] = (unsigned short)(pv >> 48);
      }
      __syncthreads();  // (c) h ready for next step
    }
  }
  // final h (fp32) for the attention query
#pragma unroll
  for (int r = 0; r < 4; ++r)
    hfin[(grp * 16 + quad * 4 + r) * H_ + kcol] = hreg[r];
}

// ---------------- K1b: q = h @ Wq^T + bq (fp32) ----------------
__global__ void k1b_q(const float* __restrict__ hfin, const float* __restrict__ Wq,
                      const float* __restrict__ bq, float* __restrict__ qbuf) {
  __shared__ float hl[H_];
  int b = blockIdx.x, j = threadIdx.x;
  hl[j] = hfin[b * H_ + j];
  __syncthreads();
  float s = bq[j];
  const float* w = Wq + j * H_;
  for (int k = 0; k < H_; ++k) s += hl[k] * w[k];
  qbuf[b * H_ + j] = s;
}

// ---------------- K2: u = tanh(enc_out@Wref^T + bref + q) @ V (fused) ----------
__launch_bounds__(512)
__global__ void k2_att(const unsigned short* __restrict__ enc_out,
                       const unsigned short* __restrict__ Wrefb,
                       const float* __restrict__ qbuf, const float* __restrict__ bref,
                       const float* __restrict__ V, float* __restrict__ ubuf) {
  __shared__ unsigned short Bs[128 * HROW];
  __shared__ float qs[128], Vs[128];
  int tid = threadIdx.x;
  int wave = tid >> 6, lane = tid & 63, quad = lane >> 4, l16 = lane & 15;
  int rowblk = blockIdx.x >> 1, nb = blockIdx.x & 1;
  int b = rowblk >> 2;
  {  // stage Wref block [nb*128 .. +128) x 256 into LDS
    int nl = tid >> 2, seg = tid & 3;
    const unsigned short* src = Wrefb + (nb * 128 + nl) * H_ + seg * 64;
    unsigned short* dst = Bs + nl * HROW + seg * 64;
#pragma unroll
    for (int i = 0; i < 8; ++i) *(u16x8*)(dst + i * 8) = *(const u16x8*)(src + i * 8);
  }
  if (tid < 128) {
    int j = nb * 128 + tid;
    qs[tid] = qbuf[b * H_ + j] + bref[j];
    Vs[tid] = V[j];
  }
  __syncthreads();
  int rw = rowblk * 128 + wave * 16 + l16;  // global (b,s) row
  const f32x4 z4 = {0.f, 0.f, 0.f, 0.f};
  f32x4 acc[8];
#pragma unroll
  for (int kt = 0; kt < 8; ++kt) {
    bf16x8 af = *(const bf16x8*)(enc_out + (size_t)rw * H_ + kt * 32 + quad * 8);
#pragma unroll
    for (int nt = 0; nt < 8; ++nt) {
      bf16x8 bfr = *(const bf16x8*)(Bs + (nt * 16 + l16) * HROW + kt * 32 + quad * 8);
      acc[nt] = __builtin_amdgcn_mfma_f32_16x16x32_bf16(af, bfr, (kt == 0) ? z4 : acc[nt],
                                                        0, 0, 0);
    }
  }
  float part[4] = {0.f, 0.f, 0.f, 0.f};
#pragma unroll
  for (int nt = 0; nt < 8; ++nt) {
    float qv = qs[nt * 16 + l16], vv = Vs[nt * 16 + l16];
#pragma unroll
    for (int r = 0; r < 4; ++r) part[r] += tanh_(acc[nt][r] + qv) * vv;
  }
#pragma unroll
  for (int m = 1; m < 16; m <<= 1) {
#pragma unroll
    for (int r = 0; r < 4; ++r) part[r] += __shfl_xor(part[r], m, 64);
  }
  if (l16 == 0) {
    int s0 = (rowblk & 3) * 128 + wave * 16 + quad * 4;
#pragma unroll
    for (int r = 0; r < 4; ++r) atomicAdd(&ubuf[b * S_ + s0 + r], part[r]);
  }
}

// ---------------- K3: softmax + glimpse + decoder head ----------------
__global__ void k3_head(const float* __restrict__ ubuf,
                        const unsigned short* __restrict__ enc_out,
                        const float* __restrict__ Wd1, const float* __restrict__ Wd2,
                        float* __restrict__ out) {
  __shared__ float sm[512];
  __shared__ float red[256];
  __shared__ float gl[256];
  int b = blockIdx.x, tid = threadIdx.x;
  float u0 = ubuf[b * S_ + tid], u1 = ubuf[b * S_ + 256 + tid];
  red[tid] = fmaxf(u0, u1);
  __syncthreads();
  for (int s = 128; s > 0; s >>= 1) {
    if (tid < s) red[tid] = fmaxf(red[tid], red[tid + s]);
    __syncthreads();
  }
  float mx = red[0];
  __syncthreads();
  float e0 = __expf(u0 - mx), e1 = __expf(u1 - mx);
  red[tid] = e0 + e1;
  __syncthreads();
  for (int s = 128; s > 0; s >>= 1) {
    if (tid < s) red[tid] += red[tid + s];
    __syncthreads();
  }
  float inv = 1.f / red[0];
  sm[tid] = e0 * inv;
  sm[256 + tid] = e1 * inv;
  __syncthreads();
  float g = 0.f;
  const unsigned short* eo = enc_out + (size_t)b * S_ * H_ + tid;
  for (int s = 0; s < S_; ++s) g += sm[s] * bf2f(eo[(size_t)s * H_]);
  gl[tid] = g;
  __syncthreads();
  float y = 0.f;
  const float* w = Wd1 + tid * H_;
  for (int j = 0; j < H_; ++j) y += w[j] * gl[j];
  y = fmaxf(y, 0.f) * Wd2[tid];
  red[tid] = y;
  __syncthreads();
  for (int s = 128; s > 0; s >>= 1) {
    if (tid < s) red[tid] += red[tid + s];
    __syncthreads();
  }
  if (tid == 0) out[b] = red[0];
}

extern "C" void kernel_launch(void* const* d_in, const int* in_sizes, int n_in,
                              void* d_out, int out_size, void* d_ws, size_t ws_size,
                              hipStream_t stream) {
  (void)in_sizes; (void)n_in; (void)out_size; (void)ws_size;
  const float* inp    = (const float*)d_in[0];
  const float* W_emb  = (const float*)d_in[1];
  const float* dec_in = (const float*)d_in[2];
  const float* eWih   = (const float*)d_in[3];
  const float* eWhh   = (const float*)d_in[4];
  const float* ebih   = (const float*)d_in[5];
  const float* ebhh   = (const float*)d_in[6];
  const float* pWih   = (const float*)d_in[7];
  const float* pWhh   = (const float*)d_in[8];
  const float* pbih   = (const float*)d_in[9];
  const float* pbhh   = (const float*)d_in[10];
  const float* Wq     = (const float*)d_in[11];
  const float* bq     = (const float*)d_in[12];
  const float* Wref   = (const float*)d_in[13];
  const float* bref   = (const float*)d_in[14];
  const float* V      = (const float*)d_in[15];
  const float* Wd1    = (const float*)d_in[16];
  const float* Wd2    = (const float*)d_in[17];
  float* out = (float*)d_out;

  char* ws = (char*)d_ws;
  unsigned short* enc_out = (unsigned short*)(ws + OFF_ENC);
  unsigned short* WhhE    = (unsigned short*)(ws + OFF_WHHE);
  unsigned short* WhhP    = (unsigned short*)(ws + OFF_WHHP);
  unsigned short* Wrefb   = (unsigned short*)(ws + OFF_WREF);
  float* Menc  = (float*)(ws + OFF_MENC);
  float* biasE = (float*)(ws + OFF_BIASE);
  float* xpv   = (float*)(ws + OFF_XPV);
  unsigned int* flags = (unsigned int*)(ws + OFF_FLAGS);
  unsigned short* hx  = (unsigned short*)(ws + OFF_HX);
  float* hfin = (float*)(ws + OFF_HFIN);
  float* qbuf = (float*)(ws + OFF_QBUF);
  float* ubuf = (float*)(ws + OFF_UBUF);

  hipLaunchKernelGGL(k0_prep, dim3(256), dim3(256), 0, stream,
                     eWih, eWhh, ebih, ebhh, pWih, pWhh, pbih, pbhh, W_emb, dec_in,
                     Wref, WhhE, WhhP, Wrefb, Menc, biasE, xpv, flags, ubuf);
  hipLaunchKernelGGL(k1_lstm, dim3(32), dim3(512), 0, stream,
                     inp, WhhE, WhhP, Menc, biasE, xpv, enc_out, hx, flags, hfin);
  hipLaunchKernelGGL(k1b_q, dim3(256), dim3(256), 0, stream, hfin, Wq, bq, qbuf);
  hipLaunchKernelGGL(k2_att, dim3(2048), dim3(512), 0, stream,
                     enc_out, Wrefb, qbuf, bref, V, ubuf);
  hipLaunchKernelGGL(k3_head, dim3(256), dim3(256), 0, stream,
                     ubuf, enc_out, Wd1, Wd2, out);
}